// Round 10
// baseline (119.582 us; speedup 1.0000x reference)
//
#include <hip/hip_runtime.h>
#include <hip/hip_cooperative_groups.h>
#include <math.h>

#define BB 4
#define NN 256
#define FCH 512
#define GCH 256
#define HID 128
#define ROWS 1024

namespace cg = cooperative_groups;

// ---------------- DPP 8-lane sum (valid at lanes with (lane&7)==0) ----------------
template <int CTRL>
__device__ __forceinline__ float dpp_add(float x) {
    const int p = __builtin_amdgcn_update_dpp(0, __float_as_int(x), CTRL, 0xF, 0xF, true);
    return x + __int_as_float(p);
}
__device__ __forceinline__ float red8(float x) {
    x = dpp_add<0xB1>(x);    // quad_perm(1,0,3,2)  = xor 1
    x = dpp_add<0x4E>(x);    // quad_perm(2,3,0,1)  = xor 2
    x = dpp_add<0x104>(x);   // row_shl:4           = lane i += lane i+4
    return x;
}

// ---------------- phase A: R5 proj body mapped onto 512 threads ----------------
// t = half(1b) x tt(8b): half = hh 0/64; within half: kq = tt>>5 (K/8), hp = tt&31.
// srow staged once (coalesced float4); W float2 loads = 2x256B/wave, read once per block;
// kq pair-combined by shfl_xor(32) (intra-wave), 4 wave-partials summed via LDS.
template <int INCH>
__device__ __forceinline__ void proj_phase(const float* __restrict__ in,
                                           const float* __restrict__ W,
                                           const float* __restrict__ bias,
                                           float* __restrict__ dst,
                                           int r0, int t,
                                           float* __restrict__ srow,
                                           float* __restrict__ partial) {
    #pragma unroll
    for (int i = 4 * t; i < 8 * INCH; i += 4 * 512)
        *(float4*)&srow[i] = *(const float4*)&in[(size_t)r0 * INCH + i];
    __syncthreads();

    const int half = t >> 8;               // 0/1 -> hh = half*64
    const int tt = t & 255;
    const int kq = tt >> 5;                // 0..7
    const int hp = tt & 31;
    const int h = half * 64 + hp * 2;
    constexpr int cpk = INCH / 8;          // f:64 g:32
    const int c0 = kq * cpk;

    float acc[8][2];
    #pragma unroll
    for (int r = 0; r < 8; ++r) { acc[r][0] = 0.f; acc[r][1] = 0.f; }

    #pragma unroll 4
    for (int cc = 0; cc < cpk; cc += 4) {
        const int c = c0 + cc;
        const float2 w0 = *(const float2*)&W[(size_t)(c + 0) * HID + h];
        const float2 w1 = *(const float2*)&W[(size_t)(c + 1) * HID + h];
        const float2 w2 = *(const float2*)&W[(size_t)(c + 2) * HID + h];
        const float2 w3 = *(const float2*)&W[(size_t)(c + 3) * HID + h];
        #pragma unroll
        for (int r = 0; r < 8; ++r) {
            const float4 s = *(const float4*)&srow[r * INCH + c];   // wave-broadcast
            acc[r][0] = fmaf(s.x, w0.x, acc[r][0]); acc[r][1] = fmaf(s.x, w0.y, acc[r][1]);
            acc[r][0] = fmaf(s.y, w1.x, acc[r][0]); acc[r][1] = fmaf(s.y, w1.y, acc[r][1]);
            acc[r][0] = fmaf(s.z, w2.x, acc[r][0]); acc[r][1] = fmaf(s.z, w2.y, acc[r][1]);
            acc[r][0] = fmaf(s.w, w3.x, acc[r][0]); acc[r][1] = fmaf(s.w, w3.y, acc[r][1]);
        }
    }

    // pair-combine kq within wave (lanes l<->l^32 share hp, adjacent kq)
    #pragma unroll
    for (int r = 0; r < 8; ++r) {
        acc[r][0] += __shfl_xor(acc[r][0], 32, 64);
        acc[r][1] += __shfl_xor(acc[r][1], 32, 64);
    }
    const int w = tt >> 6;                 // wave-in-half 0..3
    if ((tt & 63) < 32) {
        #pragma unroll
        for (int r = 0; r < 8; ++r)
            *(float2*)&partial[((half * 4 + w) * 8 + r) * 64 + hp * 2] = *(float2*)&acc[r][0];
    }
    __syncthreads();

    // tail: (half, r = tt>>5, hp2 = tt&31) -> one float2 each (512 outputs)
    {
        const int r = tt >> 5;
        const int hp2 = tt & 31;
        const int h2 = half * 64 + hp2 * 2;
        float2 s = *(const float2*)&bias[h2];
        #pragma unroll
        for (int ww = 0; ww < 4; ++ww) {
            const float2 p = *(const float2*)&partial[((half * 4 + ww) * 8 + r) * 64 + hp2 * 2];
            s.x += p.x; s.y += p.y;
        }
        *(float2*)&dst[(size_t)(r0 + r) * HID + h2] = s;
    }
}

// ---------------- fused kernel: proj -> grid.sync -> att+softmax ----------------
// USTR=40: 160B stride -> 16B-aligned ds_read_b128; hs*40 mod 32 in {0,8,16,24} -> 2-way max
#define USTR 40
#define JSTR (8 * USTR)
#define UIDX(j, h) ((j) * JSTR + ((h) >> 4) * USTR + ((h) & 15))

__global__ __launch_bounds__(512, 2) void fused_kernel(
    const float* __restrict__ feat, const float* __restrict__ gfeat,
    const float* __restrict__ adj,
    const float* __restrict__ Wf, const float* __restrict__ bf,
    const float* __restrict__ Wg, const float* __restrict__ bg,
    const float* __restrict__ Cf, const float* __restrict__ Cg,
    const float* __restrict__ a_w,
    float* __restrict__ pf, float* __restrict__ pg,
    float* __restrict__ scfg, float* __restrict__ out)
{
    __shared__ __align__(16) float srow[8 * FCH];                 // 16 KB
    __shared__ __align__(16) float partial[2 * 4 * 8 * 64];       // 16 KB
    __shared__ __align__(16) float ufc[4 * JSTR], uf2s[4 * JSTR]; // 5 KB each
    __shared__ __align__(16) float ugc[4 * JSTR], ug2s[4 * JSTR];
    __shared__ __align__(16) float att_s[4][NN];                  // 4 KB
    __shared__ float scpool[512];                                 // 2 KB

    const int t = threadIdx.x;
    const int bx = blockIdx.x;

    // ---- phase A: projection (f: blocks 0-127, g: 128-255) ----
    if (bx < 128) proj_phase<FCH>(feat, Wf, bf, pf, bx * 8, t, srow, partial);
    else          proj_phase<GCH>(gfeat, Wg, bg, pg, (bx - 128) * 8, t, srow, partial);

    // ---- scf/scg on two light g-blocks (g has half the K work of f) ----
    if (bx >= 254) {
        const float* __restrict__ C = (bx == 254) ? Cf : Cg;
        float* __restrict__ dstv = scfg + ((bx == 254) ? 0 : HID);
        const int h = t & 127;
        const int ks = t >> 7;             // 0..3
        float a = 0.f;
        #pragma unroll 4
        for (int i = 0; i < 32; ++i) {
            const int k = ks * 32 + i;
            a = fmaf(a_w[k], C[k * HID + h], a);
        }
        scpool[ks * 128 + h] = a;
        __syncthreads();
        if (t < 128)
            dstv[t] = scpool[t] + scpool[128 + t] + scpool[256 + t] + scpool[384 + t];
    }

    __threadfence();
    cg::this_grid().sync();

    // ---- phase B: att + masked softmax (R9 verbatim) ----
    const int b = bx >> 6;
    const int n0 = (bx & 63) * 4;

    {
        const int j = t >> 7;
        const int h = t & (HID - 1);
        const float sf = scfg[h];
        const float sg = scfg[HID + h];
        const float uf = pf[(size_t)(b * NN + n0 + j) * HID + h];
        const float ug = pg[(size_t)(b * NN + n0 + j) * HID + h];
        const int ui = UIDX(j, h);
        ufc[ui]  = uf * sf;
        uf2s[ui] = uf * uf;
        ugc[ui]  = ug * sg;
        ug2s[ui] = ug * ug;
    }
    __syncthreads();

    const int hs = t & 7;
    const int mg = t >> 3;
    const int m0 = mg * 4;
    const int hbase = hs * 16;

    float numf[4][4] = {}, denf[4][4] = {}, numg[4][4] = {}, deng[4][4] = {};

    #pragma unroll
    for (int it = 0; it < 4; ++it) {
        const int h = hbase + it * 4;
        float4 vf[4], vg[4], wf[4], wg[4];
        #pragma unroll
        for (int k = 0; k < 4; ++k) {
            vf[k] = *(const float4*)&pf[(size_t)(b * NN + m0 + k) * HID + h];
            vg[k] = *(const float4*)&pg[(size_t)(b * NN + m0 + k) * HID + h];
            wf[k].x = vf[k].x * vf[k].x; wf[k].y = vf[k].y * vf[k].y;
            wf[k].z = vf[k].z * vf[k].z; wf[k].w = vf[k].w * vf[k].w;
            wg[k].x = vg[k].x * vg[k].x; wg[k].y = vg[k].y * vg[k].y;
            wg[k].z = vg[k].z * vg[k].z; wg[k].w = vg[k].w * vg[k].w;
        }
        #pragma unroll
        for (int j = 0; j < 4; ++j) {
            const int ui = j * JSTR + hs * USTR + it * 4;
            const float4 c = *(const float4*)&ufc[ui];
            const float4 q = *(const float4*)&uf2s[ui];
            const float4 d = *(const float4*)&ugc[ui];
            const float4 r = *(const float4*)&ug2s[ui];
            #pragma unroll
            for (int k = 0; k < 4; ++k) {
                numf[j][k] = fmaf(vf[k].x, c.x, numf[j][k]);
                numf[j][k] = fmaf(vf[k].y, c.y, numf[j][k]);
                numf[j][k] = fmaf(vf[k].z, c.z, numf[j][k]);
                numf[j][k] = fmaf(vf[k].w, c.w, numf[j][k]);
                denf[j][k] = fmaf(wf[k].x, q.x, denf[j][k]);
                denf[j][k] = fmaf(wf[k].y, q.y, denf[j][k]);
                denf[j][k] = fmaf(wf[k].z, q.z, denf[j][k]);
                denf[j][k] = fmaf(wf[k].w, q.w, denf[j][k]);
                numg[j][k] = fmaf(vg[k].x, d.x, numg[j][k]);
                numg[j][k] = fmaf(vg[k].y, d.y, numg[j][k]);
                numg[j][k] = fmaf(vg[k].z, d.z, numg[j][k]);
                numg[j][k] = fmaf(vg[k].w, d.w, numg[j][k]);
                deng[j][k] = fmaf(wg[k].x, r.x, deng[j][k]);
                deng[j][k] = fmaf(wg[k].y, r.y, deng[j][k]);
                deng[j][k] = fmaf(wg[k].z, r.z, deng[j][k]);
                deng[j][k] = fmaf(wg[k].w, r.w, deng[j][k]);
            }
        }
    }

    #pragma unroll
    for (int j = 0; j < 4; ++j) {
        #pragma unroll
        for (int k = 0; k < 4; ++k) {
            numf[j][k] = red8(numf[j][k]);
            denf[j][k] = red8(denf[j][k]);
            numg[j][k] = red8(numg[j][k]);
            deng[j][k] = red8(deng[j][k]);
        }
    }

    if (hs == 0) {
        #pragma unroll
        for (int j = 0; j < 4; ++j) {
            const float4 ad = *(const float4*)&adj[(size_t)(b * NN + n0 + j) * NN + m0];
            float4 a4;
            a4.x = numf[j][0] / fmaxf(sqrtf(denf[j][0]), 1e-12f) + numg[j][0] / fmaxf(sqrtf(deng[j][0]), 1e-12f);
            a4.y = numf[j][1] / fmaxf(sqrtf(denf[j][1]), 1e-12f) + numg[j][1] / fmaxf(sqrtf(deng[j][1]), 1e-12f);
            a4.z = numf[j][2] / fmaxf(sqrtf(denf[j][2]), 1e-12f) + numg[j][2] / fmaxf(sqrtf(deng[j][2]), 1e-12f);
            a4.w = numf[j][3] / fmaxf(sqrtf(denf[j][3]), 1e-12f) + numg[j][3] / fmaxf(sqrtf(deng[j][3]), 1e-12f);
            if (ad.x == 0.f) a4.x -= 1e22f;
            if (ad.y == 0.f) a4.y -= 1e22f;
            if (ad.z == 0.f) a4.z -= 1e22f;
            if (ad.w == 0.f) a4.w -= 1e22f;
            *(float4*)&att_s[j][m0] = a4;
        }
    }
    __syncthreads();

    const int w = t >> 6;
    const int lane = t & 63;
    if (w < 4) {
        const float4 v = *(const float4*)&att_s[w][lane * 4];
        float mx = fmaxf(fmaxf(v.x, v.y), fmaxf(v.z, v.w));
        #pragma unroll
        for (int off = 1; off < 64; off <<= 1) mx = fmaxf(mx, __shfl_xor(mx, off, 64));
        float4 e;
        e.x = __expf(v.x - mx); e.y = __expf(v.y - mx);
        e.z = __expf(v.z - mx); e.w = __expf(v.w - mx);
        float s = e.x + e.y + e.z + e.w;
        #pragma unroll
        for (int off = 1; off < 64; off <<= 1) s += __shfl_xor(s, off, 64);
        const float inv = 1.f / s;
        float4 o;
        o.x = e.x * inv; o.y = e.y * inv; o.z = e.z * inv; o.w = e.w * inv;
        *(float4*)&out[(size_t)(b * NN + n0 + w) * NN + lane * 4] = o;
    }
}

extern "C" void kernel_launch(void* const* d_in, const int* in_sizes, int n_in,
                              void* d_out, int out_size, void* d_ws, size_t ws_size,
                              hipStream_t stream) {
    const float* feat  = (const float*)d_in[0];
    const float* gfeat = (const float*)d_in[1];
    const float* adj   = (const float*)d_in[2];
    const float* Wf    = (const float*)d_in[3];
    const float* bf    = (const float*)d_in[4];
    const float* Wg    = (const float*)d_in[5];
    const float* bg    = (const float*)d_in[6];
    const float* Cf    = (const float*)d_in[7];
    const float* Cg    = (const float*)d_in[9];
    const float* a_w   = (const float*)d_in[11];
    float* out = (float*)d_out;

    float* pf   = (float*)d_ws;                    // [ROWS][HID]
    float* pg   = pf + (size_t)ROWS * HID;         // [ROWS][HID]
    float* scfg = pg + (size_t)ROWS * HID;         // [2*HID]

    void* args[] = {&feat, &gfeat, &adj, &Wf, &bf, &Wg, &bg, &Cf, &Cg, &a_w,
                    &pf, &pg, &scfg, &out};
    hipLaunchCooperativeKernel((const void*)fused_kernel, dim3(256), dim3(512),
                               args, 0, stream);
}

// Round 11
// 75.069 us; speedup vs baseline: 1.5930x; 1.5930x over previous
//
#include <hip/hip_runtime.h>
#include <math.h>

#define BB 4
#define NN 256
#define FCH 512
#define GCH 256
#define HID 128
#define ROWS 1024
#define NBLK 256

// ---------------- DPP 8-lane sum (valid at lanes with (lane&7)==0) ----------------
template <int CTRL>
__device__ __forceinline__ float dpp_add(float x) {
    const int p = __builtin_amdgcn_update_dpp(0, __float_as_int(x), CTRL, 0xF, 0xF, true);
    return x + __int_as_float(p);
}
__device__ __forceinline__ float red8(float x) {
    x = dpp_add<0xB1>(x);    // quad_perm(1,0,3,2)  = xor 1
    x = dpp_add<0x4E>(x);    // quad_perm(2,3,0,1)  = xor 2
    x = dpp_add<0x104>(x);   // row_shl:4           = lane i += lane i+4
    return x;
}

// ---------------- lightweight grid barrier (counter zeroed by memset node) ----------------
__device__ __forceinline__ void grid_barrier(unsigned* __restrict__ ctr) {
    __syncthreads();
    if (threadIdx.x == 0) {
        __threadfence();   // release: writeback so other XCDs see pf/pg
        __hip_atomic_fetch_add(ctr, 1u, __ATOMIC_ACQ_REL, __HIP_MEMORY_SCOPE_AGENT);
        while (__hip_atomic_load(ctr, __ATOMIC_RELAXED, __HIP_MEMORY_SCOPE_AGENT) < NBLK)
            __builtin_amdgcn_s_sleep(1);
        __threadfence();   // acquire: invalidate so we read fresh pf/pg
    }
    __syncthreads();
}

// ---------------- phase A: R5 proj body mapped onto 512 threads (R10 verbatim) ----------------
template <int INCH>
__device__ __forceinline__ void proj_phase(const float* __restrict__ in,
                                           const float* __restrict__ W,
                                           const float* __restrict__ bias,
                                           float* __restrict__ dst,
                                           int r0, int t,
                                           float* __restrict__ srow,
                                           float* __restrict__ partial) {
    #pragma unroll
    for (int i = 4 * t; i < 8 * INCH; i += 4 * 512)
        *(float4*)&srow[i] = *(const float4*)&in[(size_t)r0 * INCH + i];
    __syncthreads();

    const int half = t >> 8;               // 0/1 -> hh = half*64
    const int tt = t & 255;
    const int kq = tt >> 5;                // 0..7
    const int hp = tt & 31;
    const int h = half * 64 + hp * 2;
    constexpr int cpk = INCH / 8;          // f:64 g:32
    const int c0 = kq * cpk;

    float acc[8][2];
    #pragma unroll
    for (int r = 0; r < 8; ++r) { acc[r][0] = 0.f; acc[r][1] = 0.f; }

    #pragma unroll 4
    for (int cc = 0; cc < cpk; cc += 4) {
        const int c = c0 + cc;
        const float2 w0 = *(const float2*)&W[(size_t)(c + 0) * HID + h];
        const float2 w1 = *(const float2*)&W[(size_t)(c + 1) * HID + h];
        const float2 w2 = *(const float2*)&W[(size_t)(c + 2) * HID + h];
        const float2 w3 = *(const float2*)&W[(size_t)(c + 3) * HID + h];
        #pragma unroll
        for (int r = 0; r < 8; ++r) {
            const float4 s = *(const float4*)&srow[r * INCH + c];   // wave-broadcast
            acc[r][0] = fmaf(s.x, w0.x, acc[r][0]); acc[r][1] = fmaf(s.x, w0.y, acc[r][1]);
            acc[r][0] = fmaf(s.y, w1.x, acc[r][0]); acc[r][1] = fmaf(s.y, w1.y, acc[r][1]);
            acc[r][0] = fmaf(s.z, w2.x, acc[r][0]); acc[r][1] = fmaf(s.z, w2.y, acc[r][1]);
            acc[r][0] = fmaf(s.w, w3.x, acc[r][0]); acc[r][1] = fmaf(s.w, w3.y, acc[r][1]);
        }
    }

    #pragma unroll
    for (int r = 0; r < 8; ++r) {
        acc[r][0] += __shfl_xor(acc[r][0], 32, 64);
        acc[r][1] += __shfl_xor(acc[r][1], 32, 64);
    }
    const int w = tt >> 6;                 // wave-in-half 0..3
    if ((tt & 63) < 32) {
        #pragma unroll
        for (int r = 0; r < 8; ++r)
            *(float2*)&partial[((half * 4 + w) * 8 + r) * 64 + hp * 2] = *(float2*)&acc[r][0];
    }
    __syncthreads();

    {
        const int r = tt >> 5;
        const int hp2 = tt & 31;
        const int h2 = half * 64 + hp2 * 2;
        float2 s = *(const float2*)&bias[h2];
        #pragma unroll
        for (int ww = 0; ww < 4; ++ww) {
            const float2 p = *(const float2*)&partial[((half * 4 + ww) * 8 + r) * 64 + hp2 * 2];
            s.x += p.x; s.y += p.y;
        }
        *(float2*)&dst[(size_t)(r0 + r) * HID + h2] = s;
    }
}

// ---------------- fused kernel: proj -> custom barrier -> att+softmax ----------------
#define USTR 40
#define JSTR (8 * USTR)
#define UIDX(j, h) ((j) * JSTR + ((h) >> 4) * USTR + ((h) & 15))

__global__ __launch_bounds__(512, 2) void fused_kernel(
    const float* __restrict__ feat, const float* __restrict__ gfeat,
    const float* __restrict__ adj,
    const float* __restrict__ Wf, const float* __restrict__ bf,
    const float* __restrict__ Wg, const float* __restrict__ bg,
    const float* __restrict__ Cf, const float* __restrict__ Cg,
    const float* __restrict__ a_w,
    float* __restrict__ pf, float* __restrict__ pg,
    float* __restrict__ scfg, unsigned* __restrict__ ctr,
    float* __restrict__ out)
{
    __shared__ __align__(16) float srow[8 * FCH];                 // 16 KB
    __shared__ __align__(16) float partial[2 * 4 * 8 * 64];       // 16 KB
    __shared__ __align__(16) float ufc[4 * JSTR], uf2s[4 * JSTR];
    __shared__ __align__(16) float ugc[4 * JSTR], ug2s[4 * JSTR];
    __shared__ __align__(16) float att_s[4][NN];
    __shared__ float scpool[512];

    const int t = threadIdx.x;
    const int bx = blockIdx.x;

    // ---- phase A: projection (f: blocks 0-127, g: 128-255) ----
    if (bx < 128) proj_phase<FCH>(feat, Wf, bf, pf, bx * 8, t, srow, partial);
    else          proj_phase<GCH>(gfeat, Wg, bg, pg, (bx - 128) * 8, t, srow, partial);

    // ---- scf/scg on two light g-blocks ----
    if (bx >= 254) {
        const float* __restrict__ C = (bx == 254) ? Cf : Cg;
        float* __restrict__ dstv = scfg + ((bx == 254) ? 0 : HID);
        const int h = t & 127;
        const int ks = t >> 7;
        float a = 0.f;
        #pragma unroll 4
        for (int i = 0; i < 32; ++i) {
            const int k = ks * 32 + i;
            a = fmaf(a_w[k], C[k * HID + h], a);
        }
        scpool[ks * 128 + h] = a;
        __syncthreads();
        if (t < 128)
            dstv[t] = scpool[t] + scpool[128 + t] + scpool[256 + t] + scpool[384 + t];
    }

    grid_barrier(ctr);

    // ---- phase B: att + masked softmax (R9 verbatim) ----
    const int b = bx >> 6;
    const int n0 = (bx & 63) * 4;

    {
        const int j = t >> 7;
        const int h = t & (HID - 1);
        const float sf = scfg[h];
        const float sg = scfg[HID + h];
        const float uf = pf[(size_t)(b * NN + n0 + j) * HID + h];
        const float ug = pg[(size_t)(b * NN + n0 + j) * HID + h];
        const int ui = UIDX(j, h);
        ufc[ui]  = uf * sf;
        uf2s[ui] = uf * uf;
        ugc[ui]  = ug * sg;
        ug2s[ui] = ug * ug;
    }
    __syncthreads();

    const int hs = t & 7;
    const int mg = t >> 3;
    const int m0 = mg * 4;
    const int hbase = hs * 16;

    float numf[4][4] = {}, denf[4][4] = {}, numg[4][4] = {}, deng[4][4] = {};

    #pragma unroll
    for (int it = 0; it < 4; ++it) {
        const int h = hbase + it * 4;
        float4 vf[4], vg[4], wf[4], wg[4];
        #pragma unroll
        for (int k = 0; k < 4; ++k) {
            vf[k] = *(const float4*)&pf[(size_t)(b * NN + m0 + k) * HID + h];
            vg[k] = *(const float4*)&pg[(size_t)(b * NN + m0 + k) * HID + h];
            wf[k].x = vf[k].x * vf[k].x; wf[k].y = vf[k].y * vf[k].y;
            wf[k].z = vf[k].z * vf[k].z; wf[k].w = vf[k].w * vf[k].w;
            wg[k].x = vg[k].x * vg[k].x; wg[k].y = vg[k].y * vg[k].y;
            wg[k].z = vg[k].z * vg[k].z; wg[k].w = vg[k].w * vg[k].w;
        }
        #pragma unroll
        for (int j = 0; j < 4; ++j) {
            const int ui = j * JSTR + hs * USTR + it * 4;
            const float4 c = *(const float4*)&ufc[ui];
            const float4 q = *(const float4*)&uf2s[ui];
            const float4 d = *(const float4*)&ugc[ui];
            const float4 r = *(const float4*)&ug2s[ui];
            #pragma unroll
            for (int k = 0; k < 4; ++k) {
                numf[j][k] = fmaf(vf[k].x, c.x, numf[j][k]);
                numf[j][k] = fmaf(vf[k].y, c.y, numf[j][k]);
                numf[j][k] = fmaf(vf[k].z, c.z, numf[j][k]);
                numf[j][k] = fmaf(vf[k].w, c.w, numf[j][k]);
                denf[j][k] = fmaf(wf[k].x, q.x, denf[j][k]);
                denf[j][k] = fmaf(wf[k].y, q.y, denf[j][k]);
                denf[j][k] = fmaf(wf[k].z, q.z, denf[j][k]);
                denf[j][k] = fmaf(wf[k].w, q.w, denf[j][k]);
                numg[j][k] = fmaf(vg[k].x, d.x, numg[j][k]);
                numg[j][k] = fmaf(vg[k].y, d.y, numg[j][k]);
                numg[j][k] = fmaf(vg[k].z, d.z, numg[j][k]);
                numg[j][k] = fmaf(vg[k].w, d.w, numg[j][k]);
                deng[j][k] = fmaf(wg[k].x, r.x, deng[j][k]);
                deng[j][k] = fmaf(wg[k].y, r.y, deng[j][k]);
                deng[j][k] = fmaf(wg[k].z, r.z, deng[j][k]);
                deng[j][k] = fmaf(wg[k].w, r.w, deng[j][k]);
            }
        }
    }

    #pragma unroll
    for (int j = 0; j < 4; ++j) {
        #pragma unroll
        for (int k = 0; k < 4; ++k) {
            numf[j][k] = red8(numf[j][k]);
            denf[j][k] = red8(denf[j][k]);
            numg[j][k] = red8(numg[j][k]);
            deng[j][k] = red8(deng[j][k]);
        }
    }

    if (hs == 0) {
        #pragma unroll
        for (int j = 0; j < 4; ++j) {
            const float4 ad = *(const float4*)&adj[(size_t)(b * NN + n0 + j) * NN + m0];
            float4 a4;
            a4.x = numf[j][0] / fmaxf(sqrtf(denf[j][0]), 1e-12f) + numg[j][0] / fmaxf(sqrtf(deng[j][0]), 1e-12f);
            a4.y = numf[j][1] / fmaxf(sqrtf(denf[j][1]), 1e-12f) + numg[j][1] / fmaxf(sqrtf(deng[j][1]), 1e-12f);
            a4.z = numf[j][2] / fmaxf(sqrtf(denf[j][2]), 1e-12f) + numg[j][2] / fmaxf(sqrtf(deng[j][2]), 1e-12f);
            a4.w = numf[j][3] / fmaxf(sqrtf(denf[j][3]), 1e-12f) + numg[j][3] / fmaxf(sqrtf(deng[j][3]), 1e-12f);
            if (ad.x == 0.f) a4.x -= 1e22f;
            if (ad.y == 0.f) a4.y -= 1e22f;
            if (ad.z == 0.f) a4.z -= 1e22f;
            if (ad.w == 0.f) a4.w -= 1e22f;
            *(float4*)&att_s[j][m0] = a4;
        }
    }
    __syncthreads();

    const int w = t >> 6;
    const int lane = t & 63;
    if (w < 4) {
        const float4 v = *(const float4*)&att_s[w][lane * 4];
        float mx = fmaxf(fmaxf(v.x, v.y), fmaxf(v.z, v.w));
        #pragma unroll
        for (int off = 1; off < 64; off <<= 1) mx = fmaxf(mx, __shfl_xor(mx, off, 64));
        float4 e;
        e.x = __expf(v.x - mx); e.y = __expf(v.y - mx);
        e.z = __expf(v.z - mx); e.w = __expf(v.w - mx);
        float s = e.x + e.y + e.z + e.w;
        #pragma unroll
        for (int off = 1; off < 64; off <<= 1) s += __shfl_xor(s, off, 64);
        const float inv = 1.f / s;
        float4 o;
        o.x = e.x * inv; o.y = e.y * inv; o.z = e.z * inv; o.w = e.w * inv;
        *(float4*)&out[(size_t)(b * NN + n0 + w) * NN + lane * 4] = o;
    }
}

extern "C" void kernel_launch(void* const* d_in, const int* in_sizes, int n_in,
                              void* d_out, int out_size, void* d_ws, size_t ws_size,
                              hipStream_t stream) {
    const float* feat  = (const float*)d_in[0];
    const float* gfeat = (const float*)d_in[1];
    const float* adj   = (const float*)d_in[2];
    const float* Wf    = (const float*)d_in[3];
    const float* bf    = (const float*)d_in[4];
    const float* Wg    = (const float*)d_in[5];
    const float* bg    = (const float*)d_in[6];
    const float* Cf    = (const float*)d_in[7];
    const float* Cg    = (const float*)d_in[9];
    const float* a_w   = (const float*)d_in[11];
    float* out = (float*)d_out;

    float* pf   = (float*)d_ws;                        // [ROWS][HID]
    float* pg   = pf + (size_t)ROWS * HID;             // [ROWS][HID]
    float* scfg = pg + (size_t)ROWS * HID;             // [2*HID]
    unsigned* ctr = (unsigned*)(scfg + 2 * HID + 64);  // cache-line separated

    hipMemsetAsync(ctr, 0, sizeof(unsigned), stream);

    void* args[] = {&feat, &gfeat, &adj, &Wf, &bf, &Wg, &bg, &Cf, &Cg, &a_w,
                    &pf, &pg, &scfg, &ctr, &out};
    hipLaunchCooperativeKernel((const void*)fused_kernel, dim3(NBLK), dim3(512),
                               args, 0, stream);
}

// Round 13
// 60.296 us; speedup vs baseline: 1.9833x; 1.2450x over previous
//
#include <hip/hip_runtime.h>
#include <math.h>

#define BB 4
#define NN 256
#define FCH 512
#define GCH 256
#define HID 128
#define ROWS 1024
#define NBLK 256

using f32x4 = __attribute__((ext_vector_type(4))) float;

// ---------------- device-coherent (MALL) memory ops: no L2 fences needed ----------------
__device__ __forceinline__ void store_coh(float* p, float v) {
    asm volatile("global_store_dword %0, %1, off sc0 sc1" :: "v"(p), "v"(v) : "memory");
}
__device__ __forceinline__ void wait_vm0() {
    asm volatile("s_waitcnt vmcnt(0)" ::: "memory");
}
__device__ __forceinline__ void load2_coh(const float* p0, const float* p1, float& a, float& b) {
    asm volatile("global_load_dword %0, %2, off sc0 sc1\n\t"
                 "global_load_dword %1, %3, off sc0 sc1\n\t"
                 "s_waitcnt vmcnt(0)"
                 : "=&v"(a), "=&v"(b) : "v"(p0), "v"(p1) : "memory");
}
__device__ __forceinline__ void load8x4_coh(const float* p0, const float* p1, const float* p2, const float* p3,
                                            const float* p4, const float* p5, const float* p6, const float* p7,
                                            f32x4& v0, f32x4& v1, f32x4& v2, f32x4& v3,
                                            f32x4& v4, f32x4& v5, f32x4& v6, f32x4& v7) {
    asm volatile("global_load_dwordx4 %0, %8, off sc0 sc1\n\t"
                 "global_load_dwordx4 %1, %9, off sc0 sc1\n\t"
                 "global_load_dwordx4 %2, %10, off sc0 sc1\n\t"
                 "global_load_dwordx4 %3, %11, off sc0 sc1\n\t"
                 "global_load_dwordx4 %4, %12, off sc0 sc1\n\t"
                 "global_load_dwordx4 %5, %13, off sc0 sc1\n\t"
                 "global_load_dwordx4 %6, %14, off sc0 sc1\n\t"
                 "global_load_dwordx4 %7, %15, off sc0 sc1\n\t"
                 "s_waitcnt vmcnt(0)"
                 : "=&v"(v0), "=&v"(v1), "=&v"(v2), "=&v"(v3),
                   "=&v"(v4), "=&v"(v5), "=&v"(v6), "=&v"(v7)
                 : "v"(p0), "v"(p1), "v"(p2), "v"(p3), "v"(p4), "v"(p5), "v"(p6), "v"(p7)
                 : "memory");
}

// ---------------- DPP 8-lane sum (valid at lanes with (lane&7)==0) ----------------
template <int CTRL>
__device__ __forceinline__ float dpp_add(float x) {
    const int p = __builtin_amdgcn_update_dpp(0, __float_as_int(x), CTRL, 0xF, 0xF, true);
    return x + __int_as_float(p);
}
__device__ __forceinline__ float red8(float x) {
    x = dpp_add<0xB1>(x);    // quad_perm xor1
    x = dpp_add<0x4E>(x);    // quad_perm xor2
    x = dpp_add<0x104>(x);   // row_shl:4
    return x;
}

// ---------------- fused kernel: balanced proj -> fence-free barrier -> att ----------------
#define USTR 40
#define JSTR (8 * USTR)
#define UIDX(j, h) ((j) * JSTR + ((h) >> 4) * USTR + ((h) & 15))

__global__ __launch_bounds__(512, 1) void fused_kernel(
    const float* __restrict__ feat, const float* __restrict__ gfeat,
    const float* __restrict__ adj,
    const float* __restrict__ Wf, const float* __restrict__ bf,
    const float* __restrict__ Wg, const float* __restrict__ bg,
    const float* __restrict__ Cf, const float* __restrict__ Cg,
    const float* __restrict__ a_w,
    float* __restrict__ pf, float* __restrict__ pg,
    unsigned* __restrict__ ctr, float* __restrict__ out)
{
    __shared__ __align__(16) float srowf[4 * FCH];      // 8 KB
    __shared__ __align__(16) float srowg[4 * GCH];      // 4 KB
    __shared__ __align__(16) float partialf[2048];      // 8 KB
    __shared__ __align__(16) float partialg[2048];      // 8 KB
    __shared__ float scpool[512];
    __shared__ float scf_l[HID], scg_l[HID];
    __shared__ __align__(16) float ufc[4 * JSTR], uf2s[4 * JSTR];
    __shared__ __align__(16) float ugc[4 * JSTR], ug2s[4 * JSTR];
    __shared__ __align__(16) float att_s[4][NN];

    const int t = threadIdx.x;
    const int bx = blockIdx.x;

    // ======== phase A: uniform proj (every block: 4 f-rows + 4 g-rows) ========
    const int r0 = bx * 4;
    {
        const int i = 4 * t;
        if (i < 4 * FCH)
            *(float4*)&srowf[i] = *(const float4*)&feat[(size_t)r0 * FCH + i];
        if (i < 4 * GCH)
            *(float4*)&srowg[i] = *(const float4*)&gfeat[(size_t)r0 * GCH + i];
    }
    __syncthreads();

    const int half = t >> 8;               // 0/1 -> h-halves
    const int tt = t & 255;
    const int kq = tt >> 5;                // 0..7
    const int hp = tt & 31;
    const int h = half * 64 + hp * 2;

    float af[4][2] = {{0,0},{0,0},{0,0},{0,0}};
    float ag[4][2] = {{0,0},{0,0},{0,0},{0,0}};

    {   // f: cpk = 64
        const int c0 = kq * 64;
        #pragma unroll 4
        for (int cc = 0; cc < 64; cc += 4) {
            const int c = c0 + cc;
            const float2 w0 = *(const float2*)&Wf[(size_t)(c + 0) * HID + h];
            const float2 w1 = *(const float2*)&Wf[(size_t)(c + 1) * HID + h];
            const float2 w2 = *(const float2*)&Wf[(size_t)(c + 2) * HID + h];
            const float2 w3 = *(const float2*)&Wf[(size_t)(c + 3) * HID + h];
            #pragma unroll
            for (int r = 0; r < 4; ++r) {
                const float4 s = *(const float4*)&srowf[r * FCH + c];
                af[r][0] = fmaf(s.x, w0.x, af[r][0]); af[r][1] = fmaf(s.x, w0.y, af[r][1]);
                af[r][0] = fmaf(s.y, w1.x, af[r][0]); af[r][1] = fmaf(s.y, w1.y, af[r][1]);
                af[r][0] = fmaf(s.z, w2.x, af[r][0]); af[r][1] = fmaf(s.z, w2.y, af[r][1]);
                af[r][0] = fmaf(s.w, w3.x, af[r][0]); af[r][1] = fmaf(s.w, w3.y, af[r][1]);
            }
        }
    }
    {   // g: cpk = 32
        const int c0 = kq * 32;
        #pragma unroll 4
        for (int cc = 0; cc < 32; cc += 4) {
            const int c = c0 + cc;
            const float2 w0 = *(const float2*)&Wg[(size_t)(c + 0) * HID + h];
            const float2 w1 = *(const float2*)&Wg[(size_t)(c + 1) * HID + h];
            const float2 w2 = *(const float2*)&Wg[(size_t)(c + 2) * HID + h];
            const float2 w3 = *(const float2*)&Wg[(size_t)(c + 3) * HID + h];
            #pragma unroll
            for (int r = 0; r < 4; ++r) {
                const float4 s = *(const float4*)&srowg[r * GCH + c];
                ag[r][0] = fmaf(s.x, w0.x, ag[r][0]); ag[r][1] = fmaf(s.x, w0.y, ag[r][1]);
                ag[r][0] = fmaf(s.y, w1.x, ag[r][0]); ag[r][1] = fmaf(s.y, w1.y, ag[r][1]);
                ag[r][0] = fmaf(s.z, w2.x, ag[r][0]); ag[r][1] = fmaf(s.z, w2.y, ag[r][1]);
                ag[r][0] = fmaf(s.w, w3.x, ag[r][0]); ag[r][1] = fmaf(s.w, w3.y, ag[r][1]);
            }
        }
    }

    // pair-combine kq within wave
    #pragma unroll
    for (int r = 0; r < 4; ++r) {
        af[r][0] += __shfl_xor(af[r][0], 32, 64);
        af[r][1] += __shfl_xor(af[r][1], 32, 64);
        ag[r][0] += __shfl_xor(ag[r][0], 32, 64);
        ag[r][1] += __shfl_xor(ag[r][1], 32, 64);
    }
    {
        const int w = tt >> 6;             // wave-in-half 0..3
        if ((t & 63) < 32) {
            #pragma unroll
            for (int r = 0; r < 4; ++r) {
                const int idx = ((half * 4 + w) * 4 + r) * 64 + hp * 2;
                *(float2*)&partialf[idx] = *(float2*)&af[r][0];
                *(float2*)&partialg[idx] = *(float2*)&ag[r][0];
            }
        }
    }

    // scf/scg partials (K-split 2 per matrix): which = t>>7: 0,1=f; 2,3=g
    {
        const int hh2 = t & 127;
        const int which = t >> 7;
        const float* __restrict__ C = (which < 2) ? Cf : Cg;
        const int ks = which & 1;
        float a = 0.f;
        #pragma unroll 4
        for (int k = ks * 64; k < ks * 64 + 64; ++k)
            a = fmaf(a_w[k], C[k * HID + hh2], a);
        scpool[t] = a;
    }
    __syncthreads();

    // tail: one (r,h) output per thread for f and g -> coherent store to MALL
    {
        const int r = t >> 7;
        const int hh = t & 127;
        const int hb = hh >> 6;
        const int hx = hh & 63;
        float vf = bf[hh], vg = bg[hh];
        #pragma unroll
        for (int ww = 0; ww < 4; ++ww) {
            vf += partialf[((hb * 4 + ww) * 4 + r) * 64 + hx];
            vg += partialg[((hb * 4 + ww) * 4 + r) * 64 + hx];
        }
        store_coh(pf + (size_t)(r0 + r) * HID + hh, vf);
        store_coh(pg + (size_t)(r0 + r) * HID + hh, vg);
        if (t < 128) {
            scf_l[t] = scpool[t] + scpool[128 + t];             // f: ks0 + ks1
        } else if (t < 256) {
            const int u = t - 128;
            scg_l[u] = scpool[256 + u] + scpool[384 + u];       // g: ks0 + ks1  (R12 bug fixed)
        }
    }

    // ======== fence-free grid barrier (counter zeroed by memset node) ========
    wait_vm0();                 // every wave drains its coherent stores
    __syncthreads();
    if (t == 0) {
        atomicAdd(ctr, 1u);     // device-scope atomic (no cache maintenance)
        unsigned v;
        do {
            __builtin_amdgcn_s_sleep(2);
            asm volatile("global_load_dword %0, %1, off sc0 sc1\n\ts_waitcnt vmcnt(0)"
                         : "=v"(v) : "v"(ctr) : "memory");
        } while (v < NBLK);
    }
    __syncthreads();

    // ======== phase B: att + masked softmax (R9 structure, coherent loads) ========
    const int b = bx >> 6;
    const int n0 = (bx & 63) * 4;

    {
        const int j = t >> 7;
        const int hh = t & 127;
        float uf, ug;
        load2_coh(pf + (size_t)(b * NN + n0 + j) * HID + hh,
                  pg + (size_t)(b * NN + n0 + j) * HID + hh, uf, ug);
        const float sf = scf_l[hh];
        const float sg = scg_l[hh];
        const int ui = UIDX(j, hh);
        ufc[ui]  = uf * sf;
        uf2s[ui] = uf * uf;
        ugc[ui]  = ug * sg;
        ug2s[ui] = ug * ug;
    }
    __syncthreads();

    const int hs = t & 7;
    const int mg = t >> 3;
    const int m0 = mg * 4;
    const int hbase = hs * 16;

    float numf[4][4] = {}, denf[4][4] = {}, numg[4][4] = {}, deng[4][4] = {};

    #pragma unroll
    for (int it = 0; it < 4; ++it) {
        const int hh = hbase + it * 4;
        const float* bf4 = pf + (size_t)(b * NN + m0) * HID + hh;
        const float* bg4 = pg + (size_t)(b * NN + m0) * HID + hh;
        f32x4 vf[4], vg[4], wf[4], wg[4];
        load8x4_coh(bf4, bf4 + HID, bf4 + 2 * HID, bf4 + 3 * HID,
                    bg4, bg4 + HID, bg4 + 2 * HID, bg4 + 3 * HID,
                    vf[0], vf[1], vf[2], vf[3], vg[0], vg[1], vg[2], vg[3]);
        #pragma unroll
        for (int k = 0; k < 4; ++k) { wf[k] = vf[k] * vf[k]; wg[k] = vg[k] * vg[k]; }
        #pragma unroll
        for (int j = 0; j < 4; ++j) {
            const int ui = j * JSTR + hs * USTR + it * 4;
            const float4 c = *(const float4*)&ufc[ui];
            const float4 q = *(const float4*)&uf2s[ui];
            const float4 d = *(const float4*)&ugc[ui];
            const float4 r = *(const float4*)&ug2s[ui];
            #pragma unroll
            for (int k = 0; k < 4; ++k) {
                numf[j][k] = fmaf(vf[k][0], c.x, numf[j][k]);
                numf[j][k] = fmaf(vf[k][1], c.y, numf[j][k]);
                numf[j][k] = fmaf(vf[k][2], c.z, numf[j][k]);
                numf[j][k] = fmaf(vf[k][3], c.w, numf[j][k]);
                denf[j][k] = fmaf(wf[k][0], q.x, denf[j][k]);
                denf[j][k] = fmaf(wf[k][1], q.y, denf[j][k]);
                denf[j][k] = fmaf(wf[k][2], q.z, denf[j][k]);
                denf[j][k] = fmaf(wf[k][3], q.w, denf[j][k]);
                numg[j][k] = fmaf(vg[k][0], d.x, numg[j][k]);
                numg[j][k] = fmaf(vg[k][1], d.y, numg[j][k]);
                numg[j][k] = fmaf(vg[k][2], d.z, numg[j][k]);
                numg[j][k] = fmaf(vg[k][3], d.w, numg[j][k]);
                deng[j][k] = fmaf(wg[k][0], r.x, deng[j][k]);
                deng[j][k] = fmaf(wg[k][1], r.y, deng[j][k]);
                deng[j][k] = fmaf(wg[k][2], r.z, deng[j][k]);
                deng[j][k] = fmaf(wg[k][3], r.w, deng[j][k]);
            }
        }
    }

    #pragma unroll
    for (int j = 0; j < 4; ++j) {
        #pragma unroll
        for (int k = 0; k < 4; ++k) {
            numf[j][k] = red8(numf[j][k]);
            denf[j][k] = red8(denf[j][k]);
            numg[j][k] = red8(numg[j][k]);
            deng[j][k] = red8(deng[j][k]);
        }
    }

    if (hs == 0) {
        #pragma unroll
        for (int j = 0; j < 4; ++j) {
            const float4 ad = *(const float4*)&adj[(size_t)(b * NN + n0 + j) * NN + m0];
            float4 a4;
            a4.x = numf[j][0] / fmaxf(sqrtf(denf[j][0]), 1e-12f) + numg[j][0] / fmaxf(sqrtf(deng[j][0]), 1e-12f);
            a4.y = numf[j][1] / fmaxf(sqrtf(denf[j][1]), 1e-12f) + numg[j][1] / fmaxf(sqrtf(deng[j][1]), 1e-12f);
            a4.z = numf[j][2] / fmaxf(sqrtf(denf[j][2]), 1e-12f) + numg[j][2] / fmaxf(sqrtf(deng[j][2]), 1e-12f);
            a4.w = numf[j][3] / fmaxf(sqrtf(denf[j][3]), 1e-12f) + numg[j][3] / fmaxf(sqrtf(deng[j][3]), 1e-12f);
            if (ad.x == 0.f) a4.x -= 1e22f;
            if (ad.y == 0.f) a4.y -= 1e22f;
            if (ad.z == 0.f) a4.z -= 1e22f;
            if (ad.w == 0.f) a4.w -= 1e22f;
            *(float4*)&att_s[j][m0] = a4;
        }
    }
    __syncthreads();

    const int w = t >> 6;
    const int lane = t & 63;
    if (w < 4) {
        const float4 v = *(const float4*)&att_s[w][lane * 4];
        float mx = fmaxf(fmaxf(v.x, v.y), fmaxf(v.z, v.w));
        #pragma unroll
        for (int off = 1; off < 64; off <<= 1) mx = fmaxf(mx, __shfl_xor(mx, off, 64));
        float4 e;
        e.x = __expf(v.x - mx); e.y = __expf(v.y - mx);
        e.z = __expf(v.z - mx); e.w = __expf(v.w - mx);
        float s = e.x + e.y + e.z + e.w;
        #pragma unroll
        for (int off = 1; off < 64; off <<= 1) s += __shfl_xor(s, off, 64);
        const float inv = 1.f / s;
        float4 o;
        o.x = e.x * inv; o.y = e.y * inv; o.z = e.z * inv; o.w = e.w * inv;
        *(float4*)&out[(size_t)(b * NN + n0 + w) * NN + lane * 4] = o;
    }
}

extern "C" void kernel_launch(void* const* d_in, const int* in_sizes, int n_in,
                              void* d_out, int out_size, void* d_ws, size_t ws_size,
                              hipStream_t stream) {
    const float* feat  = (const float*)d_in[0];
    const float* gfeat = (const float*)d_in[1];
    const float* adj   = (const float*)d_in[2];
    const float* Wf    = (const float*)d_in[3];
    const float* bf    = (const float*)d_in[4];
    const float* Wg    = (const float*)d_in[5];
    const float* bg    = (const float*)d_in[6];
    const float* Cf    = (const float*)d_in[7];
    const float* Cg    = (const float*)d_in[9];
    const float* a_w   = (const float*)d_in[11];
    float* out = (float*)d_out;

    float* pf = (float*)d_ws;                          // [ROWS][HID]
    float* pg = pf + (size_t)ROWS * HID;               // [ROWS][HID]
    unsigned* ctr = (unsigned*)((char*)d_ws + 2ull * ROWS * HID * sizeof(float) + 1024);

    hipMemsetAsync(ctr, 0, sizeof(unsigned), stream);

    void* args[] = {&feat, &gfeat, &adj, &Wf, &bf, &Wg, &bg, &Cf, &Cg, &a_w,
                    &pf, &pg, &ctr, &out};
    hipLaunchCooperativeKernel((const void*)fused_kernel, dim3(NBLK), dim3(512),
                               args, 0, stream);
}

// Round 14
// 33.557 us; speedup vs baseline: 3.5636x; 1.7968x over previous
//
#include <hip/hip_runtime.h>
#include <math.h>

#define BB 4
#define NN 256
#define FCH 512
#define GCH 256
#define HID 128
#define ROWS 1024

// ---------------- kernel 1: fused projection (f and g) + scf/scg (R9 verbatim) ----------------
template <int INCH>
__device__ __forceinline__ void proj_body(const float* __restrict__ in,
                                          const float* __restrict__ W,
                                          const float* __restrict__ bias,
                                          float* __restrict__ dst,
                                          int r0, int hh, int t,
                                          float* __restrict__ srow,
                                          float* __restrict__ partial) {
    #pragma unroll
    for (int i = 4 * t; i < 8 * INCH; i += 4 * 256)
        *(float4*)&srow[i] = *(const float4*)&in[(size_t)r0 * INCH + i];
    __syncthreads();

    const int kq = t >> 5;
    const int hp = t & 31;
    const int h = hh + hp * 2;
    constexpr int cpk = INCH / 8;
    const int c0 = kq * cpk;

    float acc[8][2];
    #pragma unroll
    for (int r = 0; r < 8; ++r) { acc[r][0] = 0.f; acc[r][1] = 0.f; }

    #pragma unroll 4
    for (int cc = 0; cc < cpk; cc += 4) {
        const int c = c0 + cc;
        const float2 w0 = *(const float2*)&W[(size_t)(c + 0) * HID + h];
        const float2 w1 = *(const float2*)&W[(size_t)(c + 1) * HID + h];
        const float2 w2 = *(const float2*)&W[(size_t)(c + 2) * HID + h];
        const float2 w3 = *(const float2*)&W[(size_t)(c + 3) * HID + h];
        #pragma unroll
        for (int r = 0; r < 8; ++r) {
            const float4 s = *(const float4*)&srow[r * INCH + c];
            acc[r][0] = fmaf(s.x, w0.x, acc[r][0]); acc[r][1] = fmaf(s.x, w0.y, acc[r][1]);
            acc[r][0] = fmaf(s.y, w1.x, acc[r][0]); acc[r][1] = fmaf(s.y, w1.y, acc[r][1]);
            acc[r][0] = fmaf(s.z, w2.x, acc[r][0]); acc[r][1] = fmaf(s.z, w2.y, acc[r][1]);
            acc[r][0] = fmaf(s.w, w3.x, acc[r][0]); acc[r][1] = fmaf(s.w, w3.y, acc[r][1]);
        }
    }

    #pragma unroll
    for (int r = 0; r < 8; ++r) {
        acc[r][0] += __shfl_xor(acc[r][0], 32, 64);
        acc[r][1] += __shfl_xor(acc[r][1], 32, 64);
    }
    const int w = t >> 6;
    if ((t & 63) < 32) {
        #pragma unroll
        for (int r = 0; r < 8; ++r)
            *(float2*)&partial[(((w * 8 + r) * 32) + hp) * 2] = *(float2*)&acc[r][0];
    }
    __syncthreads();

    {
        const int r = t >> 5;
        const int hp2 = t & 31;
        const int h2 = hh + hp2 * 2;
        float2 s = *(const float2*)&bias[h2];
        #pragma unroll
        for (int ww = 0; ww < 4; ++ww) {
            const float2 p = *(const float2*)&partial[(((ww * 8 + r) * 32) + hp2) * 2];
            s.x += p.x; s.y += p.y;
        }
        *(float2*)&dst[(size_t)(r0 + r) * HID + h2] = s;
    }
}

__global__ __launch_bounds__(256) void proj_fg_kernel(
    const float* __restrict__ feat, const float* __restrict__ gfeat,
    const float* __restrict__ Wf, const float* __restrict__ bf,
    const float* __restrict__ Wg, const float* __restrict__ bg,
    const float* __restrict__ Cf, const float* __restrict__ Cg,
    const float* __restrict__ a_w,
    float* __restrict__ pf, float* __restrict__ pg, float* __restrict__ scfg)
{
    __shared__ __align__(16) float srow[8 * FCH];
    __shared__ __align__(16) float partial[4 * 8 * 32 * 2];
    const int t = threadIdx.x;
    const int bx = blockIdx.x;
    if (bx == 0) {
        const float* C = (t < HID) ? Cf : Cg;
        const int h = t & (HID - 1);
        float a0 = 0.f, a1 = 0.f, a2 = 0.f, a3 = 0.f;
        #pragma unroll 4
        for (int k = 0; k < HID; k += 4) {
            a0 = fmaf(a_w[k + 0], C[(k + 0) * HID + h], a0);
            a1 = fmaf(a_w[k + 1], C[(k + 1) * HID + h], a1);
            a2 = fmaf(a_w[k + 2], C[(k + 2) * HID + h], a2);
            a3 = fmaf(a_w[k + 3], C[(k + 3) * HID + h], a3);
        }
        scfg[t] = (a0 + a1) + (a2 + a3);
        return;
    }
    if (bx <= 256) {
        const int blk = bx - 1;
        proj_body<FCH>(feat, Wf, bf, pf, (blk >> 1) * 8, (blk & 1) * 64, t, srow, partial);
    } else {
        const int blk = bx - 257;
        proj_body<GCH>(gfeat, Wg, bg, pg, (blk >> 1) * 8, (blk & 1) * 64, t, srow, partial);
    }
}

// ---------------- DPP 8-lane sum (valid at lanes with (lane&7)==0) ----------------
template <int CTRL>
__device__ __forceinline__ float dpp_add(float x) {
    const int p = __builtin_amdgcn_update_dpp(0, __float_as_int(x), CTRL, 0xF, 0xF, true);
    return x + __int_as_float(p);
}
__device__ __forceinline__ float red8(float x) {
    x = dpp_add<0xB1>(x);    // quad_perm xor1
    x = dpp_add<0x4E>(x);    // quad_perm xor2
    x = dpp_add<0x104>(x);   // row_shl:4
    return x;
}

// ---------------- kernel 2: att + masked softmax, 2n x 4m register tile ----------------
// block = 512 thr = 64 m-groups(4m) x 8 h-slices(16h); grid = BB*128 (TN=2 n-rows per block)
// USTR=40: 160B stride -> 16B-aligned ds_read_b128; hs*40 mod 32 in {0,8,16,24} -> 2-way max
#define TN 2
#define USTR 40
#define JSTR (8 * USTR)
#define UIDX(j, h) ((j) * JSTR + ((h) >> 4) * USTR + ((h) & 15))

__global__ __launch_bounds__(512, 2) void att_kernel(
    const float* __restrict__ pf, const float* __restrict__ pg,
    const float* __restrict__ adj, const float* __restrict__ scfg,
    float* __restrict__ out)
{
    __shared__ __align__(16) float ufc[TN * JSTR], uf2s[TN * JSTR];
    __shared__ __align__(16) float ugc[TN * JSTR], ug2s[TN * JSTR];
    __shared__ __align__(16) float att_s[TN][NN];

    const int t = threadIdx.x;
    const int b = blockIdx.x >> 7;
    const int n0 = (blockIdx.x & 127) * TN;

    // stage u-row derived arrays (TN rows x 128 h), 16B-aligned padded layout
    if (t < TN * HID) {
        const int j = t >> 7;
        const int h = t & (HID - 1);
        const float sf = scfg[h];
        const float sg = scfg[HID + h];
        const float uf = pf[(size_t)(b * NN + n0 + j) * HID + h];
        const float ug = pg[(size_t)(b * NN + n0 + j) * HID + h];
        const int ui = UIDX(j, h);
        ufc[ui]  = uf * sf;
        uf2s[ui] = uf * uf;
        ugc[ui]  = ug * sg;
        ug2s[ui] = ug * ug;
    }
    __syncthreads();

    const int hs = t & 7;
    const int mg = t >> 3;
    const int m0 = mg * 4;
    const int hbase = hs * 16;

    float numf[TN][4] = {}, denf[TN][4] = {}, numg[TN][4] = {}, deng[TN][4] = {};

    #pragma unroll
    for (int it = 0; it < 4; ++it) {
        const int h = hbase + it * 4;
        float4 vf[4], vg[4], wf[4], wg[4];
        #pragma unroll
        for (int k = 0; k < 4; ++k) {
            vf[k] = *(const float4*)&pf[(size_t)(b * NN + m0 + k) * HID + h];
            vg[k] = *(const float4*)&pg[(size_t)(b * NN + m0 + k) * HID + h];
            wf[k].x = vf[k].x * vf[k].x; wf[k].y = vf[k].y * vf[k].y;
            wf[k].z = vf[k].z * vf[k].z; wf[k].w = vf[k].w * vf[k].w;
            wg[k].x = vg[k].x * vg[k].x; wg[k].y = vg[k].y * vg[k].y;
            wg[k].z = vg[k].z * vg[k].z; wg[k].w = vg[k].w * vg[k].w;
        }
        #pragma unroll
        for (int j = 0; j < TN; ++j) {
            const int ui = j * JSTR + hs * USTR + it * 4;
            const float4 c = *(const float4*)&ufc[ui];
            const float4 q = *(const float4*)&uf2s[ui];
            const float4 d = *(const float4*)&ugc[ui];
            const float4 r = *(const float4*)&ug2s[ui];
            #pragma unroll
            for (int k = 0; k < 4; ++k) {
                numf[j][k] = fmaf(vf[k].x, c.x, numf[j][k]);
                numf[j][k] = fmaf(vf[k].y, c.y, numf[j][k]);
                numf[j][k] = fmaf(vf[k].z, c.z, numf[j][k]);
                numf[j][k] = fmaf(vf[k].w, c.w, numf[j][k]);
                denf[j][k] = fmaf(wf[k].x, q.x, denf[j][k]);
                denf[j][k] = fmaf(wf[k].y, q.y, denf[j][k]);
                denf[j][k] = fmaf(wf[k].z, q.z, denf[j][k]);
                denf[j][k] = fmaf(wf[k].w, q.w, denf[j][k]);
                numg[j][k] = fmaf(vg[k].x, d.x, numg[j][k]);
                numg[j][k] = fmaf(vg[k].y, d.y, numg[j][k]);
                numg[j][k] = fmaf(vg[k].z, d.z, numg[j][k]);
                numg[j][k] = fmaf(vg[k].w, d.w, numg[j][k]);
                deng[j][k] = fmaf(wg[k].x, r.x, deng[j][k]);
                deng[j][k] = fmaf(wg[k].y, r.y, deng[j][k]);
                deng[j][k] = fmaf(wg[k].z, r.z, deng[j][k]);
                deng[j][k] = fmaf(wg[k].w, r.w, deng[j][k]);
            }
        }
    }

    // reduce across the 8 h-slices: pure-VALU DPP (no DS traffic)
    #pragma unroll
    for (int j = 0; j < TN; ++j) {
        #pragma unroll
        for (int k = 0; k < 4; ++k) {
            numf[j][k] = red8(numf[j][k]);
            denf[j][k] = red8(denf[j][k]);
            numg[j][k] = red8(numg[j][k]);
            deng[j][k] = red8(deng[j][k]);
        }
    }

    if (hs == 0) {
        #pragma unroll
        for (int j = 0; j < TN; ++j) {
            const float4 ad = *(const float4*)&adj[(size_t)(b * NN + n0 + j) * NN + m0];
            float4 a4;
            a4.x = numf[j][0] / fmaxf(sqrtf(denf[j][0]), 1e-12f) + numg[j][0] / fmaxf(sqrtf(deng[j][0]), 1e-12f);
            a4.y = numf[j][1] / fmaxf(sqrtf(denf[j][1]), 1e-12f) + numg[j][1] / fmaxf(sqrtf(deng[j][1]), 1e-12f);
            a4.z = numf[j][2] / fmaxf(sqrtf(denf[j][2]), 1e-12f) + numg[j][2] / fmaxf(sqrtf(deng[j][2]), 1e-12f);
            a4.w = numf[j][3] / fmaxf(sqrtf(denf[j][3]), 1e-12f) + numg[j][3] / fmaxf(sqrtf(deng[j][3]), 1e-12f);
            if (ad.x == 0.f) a4.x -= 1e22f;
            if (ad.y == 0.f) a4.y -= 1e22f;
            if (ad.z == 0.f) a4.z -= 1e22f;
            if (ad.w == 0.f) a4.w -= 1e22f;
            *(float4*)&att_s[j][m0] = a4;
        }
    }
    __syncthreads();

    const int w = t >> 6;
    const int lane = t & 63;
    if (w < TN) {
        const float4 v = *(const float4*)&att_s[w][lane * 4];
        float mx = fmaxf(fmaxf(v.x, v.y), fmaxf(v.z, v.w));
        #pragma unroll
        for (int off = 1; off < 64; off <<= 1) mx = fmaxf(mx, __shfl_xor(mx, off, 64));
        float4 e;
        e.x = __expf(v.x - mx); e.y = __expf(v.y - mx);
        e.z = __expf(v.z - mx); e.w = __expf(v.w - mx);
        float s = e.x + e.y + e.z + e.w;
        #pragma unroll
        for (int off = 1; off < 64; off <<= 1) s += __shfl_xor(s, off, 64);
        const float inv = 1.f / s;
        float4 o;
        o.x = e.x * inv; o.y = e.y * inv; o.z = e.z * inv; o.w = e.w * inv;
        *(float4*)&out[(size_t)(b * NN + n0 + w) * NN + lane * 4] = o;
    }
}

extern "C" void kernel_launch(void* const* d_in, const int* in_sizes, int n_in,
                              void* d_out, int out_size, void* d_ws, size_t ws_size,
                              hipStream_t stream) {
    const float* feat  = (const float*)d_in[0];
    const float* gfeat = (const float*)d_in[1];
    const float* adj   = (const float*)d_in[2];
    const float* Wf    = (const float*)d_in[3];
    const float* bf    = (const float*)d_in[4];
    const float* Wg    = (const float*)d_in[5];
    const float* bg    = (const float*)d_in[6];
    const float* Cf    = (const float*)d_in[7];
    const float* Cg    = (const float*)d_in[9];
    const float* a_w   = (const float*)d_in[11];
    float* out = (float*)d_out;

    float* pf   = (float*)d_ws;                    // [ROWS][HID]
    float* pg   = pf + (size_t)ROWS * HID;         // [ROWS][HID]
    float* scfg = pg + (size_t)ROWS * HID;         // [2*HID]

    proj_fg_kernel<<<513, 256, 0, stream>>>(feat, gfeat, Wf, bf, Wg, bg,
                                            Cf, Cg, a_w, pf, pg, scfg);
    att_kernel<<<BB * 128, 512, 0, stream>>>(pf, pg, adj, scfg, out);
}

// Round 15
// 28.561 us; speedup vs baseline: 4.1870x; 1.1749x over previous
//
#include <hip/hip_runtime.h>
#include <math.h>

#define BB 4
#define NN 256
#define FCH 512
#define GCH 256
#define HID 128
#define ROWS 1024

// ---------------- kernel 1: fused projection (f and g) + scf/scg ----------------
template <int INCH>
__device__ __forceinline__ void proj_body(const float* __restrict__ in,
                                          const float* __restrict__ W,
                                          const float* __restrict__ bias,
                                          float* __restrict__ dst,
                                          int r0, int hh, int t,
                                          float* __restrict__ srow,
                                          float* __restrict__ partial) {
    #pragma unroll
    for (int i = 4 * t; i < 8 * INCH; i += 4 * 256)
        *(float4*)&srow[i] = *(const float4*)&in[(size_t)r0 * INCH + i];
    __syncthreads();

    const int kq = t >> 5;
    const int hp = t & 31;
    const int h = hh + hp * 2;
    constexpr int cpk = INCH / 8;
    const int c0 = kq * cpk;

    float acc[8][2];
    #pragma unroll
    for (int r = 0; r < 8; ++r) { acc[r][0] = 0.f; acc[r][1] = 0.f; }

    #pragma unroll 4
    for (int cc = 0; cc < cpk; cc += 4) {
        const int c = c0 + cc;
        const float2 w0 = *(const float2*)&W[(size_t)(c + 0) * HID + h];
        const float2 w1 = *(const float2*)&W[(size_t)(c + 1) * HID + h];
        const float2 w2 = *(const float2*)&W[(size_t)(c + 2) * HID + h];
        const float2 w3 = *(const float2*)&W[(size_t)(c + 3) * HID + h];
        #pragma unroll
        for (int r = 0; r < 8; ++r) {
            const float4 s = *(const float4*)&srow[r * INCH + c];
            acc[r][0] = fmaf(s.x, w0.x, acc[r][0]); acc[r][1] = fmaf(s.x, w0.y, acc[r][1]);
            acc[r][0] = fmaf(s.y, w1.x, acc[r][0]); acc[r][1] = fmaf(s.y, w1.y, acc[r][1]);
            acc[r][0] = fmaf(s.z, w2.x, acc[r][0]); acc[r][1] = fmaf(s.z, w2.y, acc[r][1]);
            acc[r][0] = fmaf(s.w, w3.x, acc[r][0]); acc[r][1] = fmaf(s.w, w3.y, acc[r][1]);
        }
    }

    #pragma unroll
    for (int r = 0; r < 8; ++r) {
        acc[r][0] += __shfl_xor(acc[r][0], 32, 64);
        acc[r][1] += __shfl_xor(acc[r][1], 32, 64);
    }
    const int w = t >> 6;
    if ((t & 63) < 32) {
        #pragma unroll
        for (int r = 0; r < 8; ++r)
            *(float2*)&partial[(((w * 8 + r) * 32) + hp) * 2] = *(float2*)&acc[r][0];
    }
    __syncthreads();

    {
        const int r = t >> 5;
        const int hp2 = t & 31;
        const int h2 = hh + hp2 * 2;
        float2 s = *(const float2*)&bias[h2];
        #pragma unroll
        for (int ww = 0; ww < 4; ++ww) {
            const float2 p = *(const float2*)&partial[(((ww * 8 + r) * 32) + hp2) * 2];
            s.x += p.x; s.y += p.y;
        }
        *(float2*)&dst[(size_t)(r0 + r) * HID + h2] = s;
    }
}

__global__ __launch_bounds__(256) void proj_fg_kernel(
    const float* __restrict__ feat, const float* __restrict__ gfeat,
    const float* __restrict__ Wf, const float* __restrict__ bf,
    const float* __restrict__ Wg, const float* __restrict__ bg,
    const float* __restrict__ Cf, const float* __restrict__ Cg,
    const float* __restrict__ a_w,
    float* __restrict__ pf, float* __restrict__ pg, float* __restrict__ scfg)
{
    __shared__ __align__(16) float srow[8 * FCH];
    __shared__ __align__(16) float partial[4 * 8 * 32 * 2];
    const int t = threadIdx.x;
    const int bx = blockIdx.x;
    if (bx == 0) {
        const float* C = (t < HID) ? Cf : Cg;
        const int h = t & (HID - 1);
        float a0 = 0.f, a1 = 0.f, a2 = 0.f, a3 = 0.f;
        #pragma unroll 4
        for (int k = 0; k < HID; k += 4) {
            a0 = fmaf(a_w[k + 0], C[(k + 0) * HID + h], a0);
            a1 = fmaf(a_w[k + 1], C[(k + 1) * HID + h], a1);
            a2 = fmaf(a_w[k + 2], C[(k + 2) * HID + h], a2);
            a3 = fmaf(a_w[k + 3], C[(k + 3) * HID + h], a3);
        }
        scfg[t] = (a0 + a1) + (a2 + a3);
        return;
    }
    if (bx <= 256) {
        const int blk = bx - 1;
        proj_body<FCH>(feat, Wf, bf, pf, (blk >> 1) * 8, (blk & 1) * 64, t, srow, partial);
    } else {
        const int blk = bx - 257;
        proj_body<GCH>(gfeat, Wg, bg, pg, (blk >> 1) * 8, (blk & 1) * 64, t, srow, partial);
    }
}

// ---------------- DPP 8-lane sum (valid at lanes with (lane&7)==0) ----------------
template <int CTRL>
__device__ __forceinline__ float dpp_add(float x) {
    const int p = __builtin_amdgcn_update_dpp(0, __float_as_int(x), CTRL, 0xF, 0xF, true);
    return x + __int_as_float(p);
}
__device__ __forceinline__ float red8(float x) {
    x = dpp_add<0xB1>(x);    // quad_perm xor1
    x = dpp_add<0x4E>(x);    // quad_perm xor2
    x = dpp_add<0x104>(x);   // row_shl:4
    return x;
}

// ---------------- kernel 2: att + masked softmax, 4n x 4m register tile ----------------
// block = 512 thr = 64 m-groups(4m) x 8 h-slices(16h); grid = BB*64 (4 n-rows per block)
// USTR=40: 160B stride -> 16B-aligned ds_read_b128; hs*40 mod 32 in {0,8,16,24} -> 2-way max
#define USTR 40
#define JSTR (8 * USTR)
#define UIDX(j, h) ((j) * JSTR + ((h) >> 4) * USTR + ((h) & 15))

__global__ __launch_bounds__(512, 2) void att_kernel(
    const float* __restrict__ pf, const float* __restrict__ pg,
    const float* __restrict__ adj, const float* __restrict__ scfg,
    float* __restrict__ out)
{
    __shared__ __align__(16) float ufc[4 * JSTR], uf2s[4 * JSTR];
    __shared__ __align__(16) float ugc[4 * JSTR], ug2s[4 * JSTR];
    __shared__ __align__(16) float att_s[4][NN];

    const int t = threadIdx.x;
    const int b = blockIdx.x >> 6;
    const int n0 = (blockIdx.x & 63) * 4;

    // stage u-row derived arrays (4 rows x 128 h), 16B-aligned padded layout
    {
        const int j = t >> 7;
        const int h = t & (HID - 1);
        const float sf = scfg[h];
        const float sg = scfg[HID + h];
        const float uf = pf[(size_t)(b * NN + n0 + j) * HID + h];
        const float ug = pg[(size_t)(b * NN + n0 + j) * HID + h];
        const int ui = UIDX(j, h);
        ufc[ui]  = uf * sf;
        uf2s[ui] = uf * uf;
        ugc[ui]  = ug * sg;
        ug2s[ui] = ug * ug;
    }
    __syncthreads();

    const int hs = t & 7;
    const int mg = t >> 3;
    const int m0 = mg * 4;
    const int hbase = hs * 16;

    float numf[4][4] = {}, denf[4][4] = {}, numg[4][4] = {}, deng[4][4] = {};

    #pragma unroll
    for (int it = 0; it < 4; ++it) {
        const int h = hbase + it * 4;
        float4 vf[4], vg[4], wf[4], wg[4];
        #pragma unroll
        for (int k = 0; k < 4; ++k) {
            vf[k] = *(const float4*)&pf[(size_t)(b * NN + m0 + k) * HID + h];
            vg[k] = *(const float4*)&pg[(size_t)(b * NN + m0 + k) * HID + h];
            wf[k].x = vf[k].x * vf[k].x; wf[k].y = vf[k].y * vf[k].y;
            wf[k].z = vf[k].z * vf[k].z; wf[k].w = vf[k].w * vf[k].w;
            wg[k].x = vg[k].x * vg[k].x; wg[k].y = vg[k].y * vg[k].y;
            wg[k].z = vg[k].z * vg[k].z; wg[k].w = vg[k].w * vg[k].w;
        }
        #pragma unroll
        for (int j = 0; j < 4; ++j) {
            const int ui = j * JSTR + hs * USTR + it * 4;
            const float4 c = *(const float4*)&ufc[ui];
            const float4 q = *(const float4*)&uf2s[ui];
            const float4 d = *(const float4*)&ugc[ui];
            const float4 r = *(const float4*)&ug2s[ui];
            #pragma unroll
            for (int k = 0; k < 4; ++k) {
                numf[j][k] = fmaf(vf[k].x, c.x, numf[j][k]);
                numf[j][k] = fmaf(vf[k].y, c.y, numf[j][k]);
                numf[j][k] = fmaf(vf[k].z, c.z, numf[j][k]);
                numf[j][k] = fmaf(vf[k].w, c.w, numf[j][k]);
                denf[j][k] = fmaf(wf[k].x, q.x, denf[j][k]);
                denf[j][k] = fmaf(wf[k].y, q.y, denf[j][k]);
                denf[j][k] = fmaf(wf[k].z, q.z, denf[j][k]);
                denf[j][k] = fmaf(wf[k].w, q.w, denf[j][k]);
                numg[j][k] = fmaf(vg[k].x, d.x, numg[j][k]);
                numg[j][k] = fmaf(vg[k].y, d.y, numg[j][k]);
                numg[j][k] = fmaf(vg[k].z, d.z, numg[j][k]);
                numg[j][k] = fmaf(vg[k].w, d.w, numg[j][k]);
                deng[j][k] = fmaf(wg[k].x, r.x, deng[j][k]);
                deng[j][k] = fmaf(wg[k].y, r.y, deng[j][k]);
                deng[j][k] = fmaf(wg[k].z, r.z, deng[j][k]);
                deng[j][k] = fmaf(wg[k].w, r.w, deng[j][k]);
            }
        }
    }

    // reduce across the 8 h-slices: pure-VALU DPP (no DS traffic)
    #pragma unroll
    for (int j = 0; j < 4; ++j) {
        #pragma unroll
        for (int k = 0; k < 4; ++k) {
            numf[j][k] = red8(numf[j][k]);
            denf[j][k] = red8(denf[j][k]);
            numg[j][k] = red8(numg[j][k]);
            deng[j][k] = red8(deng[j][k]);
        }
    }

    if (hs == 0) {
        #pragma unroll
        for (int j = 0; j < 4; ++j) {
            const float4 ad = *(const float4*)&adj[(size_t)(b * NN + n0 + j) * NN + m0];
            float4 a4;
            a4.x = numf[j][0] / fmaxf(sqrtf(denf[j][0]), 1e-12f) + numg[j][0] / fmaxf(sqrtf(deng[j][0]), 1e-12f);
            a4.y = numf[j][1] / fmaxf(sqrtf(denf[j][1]), 1e-12f) + numg[j][1] / fmaxf(sqrtf(deng[j][1]), 1e-12f);
            a4.z = numf[j][2] / fmaxf(sqrtf(denf[j][2]), 1e-12f) + numg[j][2] / fmaxf(sqrtf(deng[j][2]), 1e-12f);
            a4.w = numf[j][3] / fmaxf(sqrtf(denf[j][3]), 1e-12f) + numg[j][3] / fmaxf(sqrtf(deng[j][3]), 1e-12f);
            if (ad.x == 0.f) a4.x -= 1e22f;
            if (ad.y == 0.f) a4.y -= 1e22f;
            if (ad.z == 0.f) a4.z -= 1e22f;
            if (ad.w == 0.f) a4.w -= 1e22f;
            *(float4*)&att_s[j][m0] = a4;
        }
    }
    __syncthreads();

    const int w = t >> 6;
    const int lane = t & 63;
    if (w < 4) {
        const float4 v = *(const float4*)&att_s[w][lane * 4];
        float mx = fmaxf(fmaxf(v.x, v.y), fmaxf(v.z, v.w));
        #pragma unroll
        for (int off = 1; off < 64; off <<= 1) mx = fmaxf(mx, __shfl_xor(mx, off, 64));
        float4 e;
        e.x = __expf(v.x - mx); e.y = __expf(v.y - mx);
        e.z = __expf(v.z - mx); e.w = __expf(v.w - mx);
        float s = e.x + e.y + e.z + e.w;
        #pragma unroll
        for (int off = 1; off < 64; off <<= 1) s += __shfl_xor(s, off, 64);
        const float inv = 1.f / s;
        float4 o;
        o.x = e.x * inv; o.y = e.y * inv; o.z = e.z * inv; o.w = e.w * inv;
        *(float4*)&out[(size_t)(b * NN + n0 + w) * NN + lane * 4] = o;
    }
}

extern "C" void kernel_launch(void* const* d_in, const int* in_sizes, int n_in,
                              void* d_out, int out_size, void* d_ws, size_t ws_size,
                              hipStream_t stream) {
    const float* feat  = (const float*)d_in[0];
    const float* gfeat = (const float*)d_in[1];
    const float* adj   = (const float*)d_in[2];
    const float* Wf    = (const float*)d_in[3];
    const float* bf    = (const float*)d_in[4];
    const float* Wg    = (const float*)d_in[5];
    const float* bg    = (const float*)d_in[6];
    const float* Cf    = (const float*)d_in[7];
    const float* Cg    = (const float*)d_in[9];
    const float* a_w   = (const float*)d_in[11];
    float* out = (float*)d_out;

    float* pf   = (float*)d_ws;                    // [ROWS][HID]
    float* pg   = pf + (size_t)ROWS * HID;         // [ROWS][HID]
    float* scfg = pg + (size_t)ROWS * HID;         // [2*HID]

    proj_fg_kernel<<<513, 256, 0, stream>>>(feat, gfeat, Wf, bf, Wg, bg,
                                            Cf, Cg, a_w, pf, pg, scfg);
    att_kernel<<<BB * 64, 512, 0, stream>>>(pf, pg, adj, scfg, out);
}